// Round 1
// baseline (123.904 us; speedup 1.0000x reference)
//
#include <hip/hip_runtime.h>

// Problem constants (from reference): B=4, N=64, S=512, D=128, H=8
#define Bsz 4
#define Ngrp 64
#define Sset 512
#define Din 128
#define Hh 8
#define EST (Sset + 1)  // padded LDS stride for e rows

// -----------------------------------------------------------------------------
// Kernel A: u[h][d] = sum_k W[d, h*D+k] * q[h, k]   (only first D rows of W
// matter; the set-feature half of W contributes a per-(b,n,h) constant that
// cancels in the softmax over s)
// -----------------------------------------------------------------------------
__global__ void __launch_bounds__(Din) compute_u_kernel(
    const float* __restrict__ W,   // (2D, H*D) row-major
    const float* __restrict__ q,   // (H, D)
    float* __restrict__ u)         // (H, D) out
{
    const int h = blockIdx.x;    // 0..7
    const int d = threadIdx.x;   // 0..127

    __shared__ float qs[Din];
    qs[d] = q[h * Din + d];
    __syncthreads();

    const float4* Wr = (const float4*)(W + (size_t)d * (Hh * Din) + (size_t)h * Din);
    const float4* q4 = (const float4*)qs;

    float acc = 0.f;
#pragma unroll
    for (int j = 0; j < Din / 4; ++j) {
        float4 wv = Wr[j];
        float4 qv = q4[j];
        acc = fmaf(wv.x, qv.x, acc);
        acc = fmaf(wv.y, qv.y, acc);
        acc = fmaf(wv.z, qv.z, acc);
        acc = fmaf(wv.w, qv.w, acc);
    }
    u[h * Din + d] = acc;
}

// -----------------------------------------------------------------------------
// Kernel B: per (b,n) block: e[s][h] = x[b,n,s,:]·u[h,:], softmax over s,
// write out (B,N,S,H).
// -----------------------------------------------------------------------------
__global__ void __launch_bounds__(Sset) attn_softmax_kernel(
    const float* __restrict__ x,    // (B,N,S,D)
    const float* __restrict__ u,    // (H,D)
    float* __restrict__ out)        // (B,N,S,H)
{
    const int bn = blockIdx.x;      // 0..255
    const int tid = threadIdx.x;    // 0..511

    __shared__ float e_s[Hh * EST];

    // ---- Phase 1: e[s][h] dot products; one s-row per thread -------------
    {
        const int s = tid;
        const float4* xr = (const float4*)(x + ((size_t)bn * Sset + s) * Din);
        const float4* u4 = (const float4*)u;   // uniform addresses -> s_load

        float acc[Hh];
#pragma unroll
        for (int h = 0; h < Hh; ++h) acc[h] = 0.f;

#pragma unroll 4
        for (int j = 0; j < Din / 4; ++j) {
            float4 xv = xr[j];
#pragma unroll
            for (int h = 0; h < Hh; ++h) {
                float4 wv = u4[h * (Din / 4) + j];
                acc[h] = fmaf(xv.x, wv.x, acc[h]);
                acc[h] = fmaf(xv.y, wv.y, acc[h]);
                acc[h] = fmaf(xv.z, wv.z, acc[h]);
                acc[h] = fmaf(xv.w, wv.w, acc[h]);
            }
        }
#pragma unroll
        for (int h = 0; h < Hh; ++h) e_s[h * EST + s] = acc[h];
    }
    __syncthreads();

    // ---- Phase 2: softmax over s; wave w handles head w ------------------
    {
        const int w = tid >> 6;        // 0..7 (8 waves == 8 heads)
        const int lane = tid & 63;
        float* eh = &e_s[w * EST];

        float m = -1e30f;
#pragma unroll
        for (int k = 0; k < Sset / 64; ++k) m = fmaxf(m, eh[lane + 64 * k]);
#pragma unroll
        for (int off = 32; off >= 1; off >>= 1) m = fmaxf(m, __shfl_xor(m, off, 64));

        float p[Sset / 64];
        float sum = 0.f;
#pragma unroll
        for (int k = 0; k < Sset / 64; ++k) {
            p[k] = __expf(eh[lane + 64 * k] - m);
            sum += p[k];
        }
#pragma unroll
        for (int off = 32; off >= 1; off >>= 1) sum += __shfl_xor(sum, off, 64);

        const float inv = 1.f / sum;
#pragma unroll
        for (int k = 0; k < Sset / 64; ++k) eh[lane + 64 * k] = p[k] * inv;
    }
    __syncthreads();

    // ---- Phase 3: coalesced write out[(bn*S + s)*H + h] ------------------
    {
        const int s = tid;
        float4 o0, o1;
        o0.x = e_s[0 * EST + s];
        o0.y = e_s[1 * EST + s];
        o0.z = e_s[2 * EST + s];
        o0.w = e_s[3 * EST + s];
        o1.x = e_s[4 * EST + s];
        o1.y = e_s[5 * EST + s];
        o1.z = e_s[6 * EST + s];
        o1.w = e_s[7 * EST + s];
        float4* orow = (float4*)(out + ((size_t)bn * Sset + s) * Hh);
        orow[0] = o0;
        orow[1] = o1;
    }
}

extern "C" void kernel_launch(void* const* d_in, const int* in_sizes, int n_in,
                              void* d_out, int out_size, void* d_ws, size_t ws_size,
                              hipStream_t stream) {
    // setup_inputs order: x, w1, b1, w2, b2, w3, b3, W, Wb, q
    const float* x = (const float*)d_in[0];
    const float* W = (const float*)d_in[7];
    const float* q = (const float*)d_in[9];
    float* u = (float*)d_ws;            // H*D floats = 4 KB scratch
    float* out = (float*)d_out;

    compute_u_kernel<<<dim3(Hh), dim3(Din), 0, stream>>>(W, q, u);
    attn_softmax_kernel<<<dim3(Bsz * Ngrp), dim3(Sset), 0, stream>>>(x, u, out);
}